// Round 1
// baseline (346.741 us; speedup 1.0000x reference)
//
#include <hip/hip_runtime.h>
#include <hip/hip_bf16.h>

#define H 1024
#define BATCH 16384

typedef unsigned short u16;
typedef u16 u16x8 __attribute__((ext_vector_type(8)));
typedef __bf16 bf16x8 __attribute__((ext_vector_type(8)));
typedef float f32x4 __attribute__((ext_vector_type(4)));

__device__ __forceinline__ u16 f2bf(float f) {
  unsigned int u = __float_as_uint(f);
  u += 0x7fffu + ((u >> 16) & 1u);   // round-to-nearest-even
  return (u16)(u >> 16);
}

// ---- K1: column sums of x (x_mean * B) ----
__global__ __launch_bounds__(256) void colsum_kernel(const float* __restrict__ x,
                                                     float* __restrict__ xsum) {
  int col = blockIdx.x * 256 + threadIdx.x;
  size_t r0 = (size_t)blockIdx.y * 256;
  float s = 0.f;
#pragma unroll 8
  for (int r = 0; r < 256; ++r) s += x[(r0 + r) * H + col];
  atomicAdd(&xsum[col], s);
}

// ---- K2: output = (x @ W) * meta, bf16 MFMA 16x16x32 ----
// block = 256 threads = 4 waves, tile 128x128, BK=32
// wave (wm,wn) in 2x2, each computes 64x64 as 4x4 frags of 16x16
__global__ __launch_bounds__(256) void gemm_kernel(const float* __restrict__ X,
                                                   const float* __restrict__ W,
                                                   const float* __restrict__ meta,
                                                   float* __restrict__ out) {
  __shared__ __align__(16) u16 lA[128][40];  // [m][k], +8 pad
  __shared__ __align__(16) u16 lB[128][40];  // [n][k] (W transposed), +8 pad

  const int tid = threadIdx.x;
  const int wave = tid >> 6;
  const int lane = tid & 63;
  const int quad = lane >> 4;
  const int l16 = lane & 15;
  const int wm = wave >> 1, wn = wave & 1;
  const size_t row0 = (size_t)blockIdx.x * 128;  // M tile
  const int col0 = blockIdx.y * 128;             // N tile

  f32x4 acc[4][4];
#pragma unroll
  for (int i = 0; i < 4; ++i)
#pragma unroll
    for (int j = 0; j < 4; ++j) acc[i][j] = (f32x4){0.f, 0.f, 0.f, 0.f};

  for (int k0 = 0; k0 < H; k0 += 32) {
    // stage A: x[row0..row0+127][k0..k0+31] -> lA (bf16)
#pragma unroll
    for (int i = 0; i < 4; ++i) {
      int idx = i * 256 + tid;          // 0..1023
      int r = idx >> 3, c4 = idx & 7;   // 128 rows x 8 float4
      const float4 v = *(const float4*)&X[(row0 + r) * H + k0 + c4 * 4];
      ushort4 h;
      h.x = f2bf(v.x); h.y = f2bf(v.y); h.z = f2bf(v.z); h.w = f2bf(v.w);
      *(ushort4*)&lA[r][c4 * 4] = h;
    }
    // stage B transposed: W[k0+kk][col0+c] -> lB[c][kk]
#pragma unroll
    for (int i = 0; i < 4; ++i) {
      int idx = i * 256 + tid;            // 0..1023
      int kk = idx >> 5, c4 = idx & 31;   // 32 k-rows x 32 float4
      const float4 v = *(const float4*)&W[(size_t)(k0 + kk) * H + col0 + c4 * 4];
      lB[c4 * 4 + 0][kk] = f2bf(v.x);
      lB[c4 * 4 + 1][kk] = f2bf(v.y);
      lB[c4 * 4 + 2][kk] = f2bf(v.z);
      lB[c4 * 4 + 3][kk] = f2bf(v.w);
    }
    __syncthreads();

    bf16x8 av[4], bv[4];
#pragma unroll
    for (int f = 0; f < 4; ++f) {
      av[f] = __builtin_bit_cast(bf16x8, *(const u16x8*)&lA[wm * 64 + f * 16 + l16][quad * 8]);
      bv[f] = __builtin_bit_cast(bf16x8, *(const u16x8*)&lB[wn * 64 + f * 16 + l16][quad * 8]);
    }
#pragma unroll
    for (int fm = 0; fm < 4; ++fm)
#pragma unroll
      for (int fn = 0; fn < 4; ++fn)
        acc[fm][fn] = __builtin_amdgcn_mfma_f32_16x16x32_bf16(av[fm], bv[fn], acc[fm][fn], 0, 0, 0);
    __syncthreads();
  }

  // epilogue: scale by meta[col], store fp32
  float mcol[4];
#pragma unroll
  for (int fn = 0; fn < 4; ++fn) mcol[fn] = meta[col0 + wn * 64 + fn * 16 + l16];
#pragma unroll
  for (int fm = 0; fm < 4; ++fm) {
#pragma unroll
    for (int fn = 0; fn < 4; ++fn) {
      int col = col0 + wn * 64 + fn * 16 + l16;
#pragma unroll
      for (int r = 0; r < 4; ++r) {
        size_t row = row0 + wm * 64 + fm * 16 + quad * 4 + r;
        out[row * H + col] = acc[fm][fn][r] * mcol[fn];
      }
    }
  }
}

// ---- K3: out_raw[j] = sum_k x_mean[k] * W[k][j]  (fp32, exact) ----
__global__ __launch_bounds__(256) void vecmat_kernel(const float* __restrict__ W,
                                                     const float* __restrict__ xsum,
                                                     float* __restrict__ outraw) {
  int j = blockIdx.x * 256 + threadIdx.x;
  int k0 = blockIdx.y * 64;
  float s = 0.f;
#pragma unroll 8
  for (int k = 0; k < 64; ++k) s += xsum[k0 + k] * W[(size_t)(k0 + k) * H + j];
  atomicAdd(&outraw[j], s * (1.0f / (float)BATCH));
}

// ---- K4: STDP weighted history sums ----
// posv[c]  = sum_{t=1..99} w[t-1] * pre_hist[t][c]
// negh[c]  = sum_{t=2..99} w[t-1] * post_hist[t][c]
// w[i] = 0.01*exp(-(100-i)*window*decay)  => w[t-1] = 0.01*exp(-(101-t)*wd)
__global__ __launch_bounds__(256) void stdpvec_kernel(const float* __restrict__ pre,
                                                      const float* __restrict__ post,
                                                      const float* __restrict__ win,
                                                      const float* __restrict__ dec,
                                                      float* __restrict__ posv,
                                                      float* __restrict__ negh) {
  int col = blockIdx.x * 256 + threadIdx.x;
  int t0 = 1 + blockIdx.y * 20;
  float wd = win[0] * dec[0];
  float ps = 0.f, ns = 0.f;
  int tend = t0 + 20;
  if (tend > 100) tend = 100;
  for (int t = t0; t < tend; ++t) {
    float w = 0.01f * expf(-(float)(101 - t) * wd);
    ps += w * pre[t * H + col];
    if (t >= 2) ns += w * post[t * H + col];
  }
  atomicAdd(&posv[col], ps);
  atomicAdd(&negh[col], ns);
}

// ---- K5: scalars, new_meta, hist ----
__global__ __launch_bounds__(1024) void finalize_kernel(const float* __restrict__ meta,
                                                        const float* __restrict__ act,
                                                        const int* __restrict__ ptr,
                                                        const float* __restrict__ targ,
                                                        const float* __restrict__ homeo,
                                                        const float* __restrict__ mlr,
                                                        const float* __restrict__ outraw,
                                                        float* __restrict__ outmean,
                                                        float* __restrict__ scalep,
                                                        float* __restrict__ meta_out,
                                                        float* __restrict__ hist_out) {
  __shared__ float r1[16], r2[16];
  __shared__ float sc[2];
  int t = threadIdx.x;
  float om = meta[t] * outraw[t];
  outmean[t] = om;
  float a = (t < 1000) ? act[t] : 0.f;
  float s1 = om, s2 = a;
#pragma unroll
  for (int o = 32; o > 0; o >>= 1) {
    s1 += __shfl_down(s1, o, 64);
    s2 += __shfl_down(s2, o, 64);
  }
  if ((t & 63) == 0) { r1[t >> 6] = s1; r2[t >> 6] = s2; }
  __syncthreads();
  if (t == 0) {
    float ts1 = 0.f, ts2 = 0.f;
#pragma unroll
    for (int i = 0; i < 16; ++i) { ts1 += r1[i]; ts2 += r2[i]; }
    float total_mean = ts1 / (float)H;       // mean over all B*H of output
    int p = ptr[0];
    float hist_mean = (ts2 - act[p] + total_mean) / 1000.f;
    float diff = targ[0] - hist_mean;
    sc[0] = 1.f + homeo[0] * diff;
    sc[1] = total_mean;
    scalep[0] = sc[0];
  }
  __syncthreads();
  float nm = meta[t] + mlr[0] * (om - meta[t]);
  nm = fminf(fmaxf(nm, 0.f), 2.f);
  meta_out[t] = nm;
  if (t < 1000) hist_out[t] = (t == ptr[0]) ? sc[1] : act[t];
}

// ---- K6: new_w = clip(clip(W + dW, -1,1)*scale, -1,1) ----
__global__ __launch_bounds__(256) void neww_kernel(const float* __restrict__ W,
                                                   const float* __restrict__ outmean,
                                                   const float* __restrict__ posv,
                                                   const float* __restrict__ negh,
                                                   const float* __restrict__ xsum,
                                                   const float* __restrict__ scalep,
                                                   const float* __restrict__ win,
                                                   const float* __restrict__ dec,
                                                   float* __restrict__ out) {
  int idx = blockIdx.x * 256 + threadIdx.x;
  int rr = idx >> 10;
  int cc = idx & 1023;
  float w99 = 0.01f * expf(-win[0] * dec[0]);
  float scale = scalep[0];
  float om_r = outmean[rr];
  float neg_r = negh[rr] + w99 * om_r;
  float v = W[idx] + om_r * posv[cc] - neg_r * (xsum[cc] * (1.0f / (float)BATCH));
  v = fminf(fmaxf(v, -1.f), 1.f);
  v = v * scale;
  v = fminf(fmaxf(v, -1.f), 1.f);
  out[idx] = v;
}

extern "C" void kernel_launch(void* const* d_in, const int* in_sizes, int n_in,
                              void* d_out, int out_size, void* d_ws, size_t ws_size,
                              hipStream_t stream) {
  const float* x     = (const float*)d_in[0];
  const float* W     = (const float*)d_in[1];
  const float* meta  = (const float*)d_in[2];
  const float* pre   = (const float*)d_in[3];
  const float* post  = (const float*)d_in[4];
  const float* act   = (const float*)d_in[5];
  const int*   ptr   = (const int*)d_in[6];
  const float* win   = (const float*)d_in[7];
  const float* dec   = (const float*)d_in[8];
  const float* targ  = (const float*)d_in[9];
  const float* homeo = (const float*)d_in[10];
  const float* mlr   = (const float*)d_in[11];

  float* out_y    = (float*)d_out;              // [B,H]
  float* out_w    = out_y + (size_t)BATCH * H;  // [H,H]
  float* out_meta = out_w + (size_t)H * H;      // [H]
  float* out_hist = out_meta + H;               // [1000]

  float* ws      = (float*)d_ws;
  float* xsum    = ws;          // H
  float* outraw  = ws + 1024;   // H
  float* outmean = ws + 2048;   // H
  float* posv    = ws + 3072;   // H
  float* negh    = ws + 4096;   // H
  float* scalep  = ws + 5120;   // 2

  hipMemsetAsync(d_ws, 0, 6144 * sizeof(float), stream);

  colsum_kernel<<<dim3(4, 64), 256, 0, stream>>>(x, xsum);
  gemm_kernel<<<dim3(128, 8), 256, 0, stream>>>(x, W, meta, out_y);
  vecmat_kernel<<<dim3(4, 16), 256, 0, stream>>>(W, xsum, outraw);
  stdpvec_kernel<<<dim3(4, 5), 256, 0, stream>>>(pre, post, win, dec, posv, negh);
  finalize_kernel<<<1, 1024, 0, stream>>>(meta, act, ptr, targ, homeo, mlr,
                                          outraw, outmean, scalep, out_meta, out_hist);
  neww_kernel<<<4096, 256, 0, stream>>>(W, outmean, posv, negh, xsum, scalep, win, dec, out_w);
}

// Round 2
// 242.189 us; speedup vs baseline: 1.4317x; 1.4317x over previous
//
#include <hip/hip_runtime.h>
#include <hip/hip_bf16.h>

#define H 1024
#define BATCH 16384

typedef unsigned short u16;
typedef u16 u16x8 __attribute__((ext_vector_type(8)));
typedef __bf16 bf16x8 __attribute__((ext_vector_type(8)));
typedef float f32x4 __attribute__((ext_vector_type(4)));

typedef __attribute__((address_space(3))) unsigned int lds_uint;
typedef __attribute__((address_space(1))) const unsigned int glob_uint;

__device__ __forceinline__ u16 f2bf(float f) {
  unsigned int u = __float_as_uint(f);
  u += 0x7fffu + ((u >> 16) & 1u);   // round-to-nearest-even
  return (u16)(u >> 16);
}

// ---- K1: convert X fp32 -> bf16, fused column sums ----
// block handles 64 rows x all 1024 cols; thread t owns cols 4t..4t+3
__global__ __launch_bounds__(256) void convx_kernel(const float* __restrict__ X,
                                                    u16* __restrict__ Xb,
                                                    float* __restrict__ xsum) {
  size_t r0 = (size_t)blockIdx.x * 64;
  int c = threadIdx.x;
  float s0 = 0.f, s1 = 0.f, s2 = 0.f, s3 = 0.f;
#pragma unroll 4
  for (int r = 0; r < 64; ++r) {
    size_t off = (r0 + r) * H + c * 4;
    const float4 v = *(const float4*)&X[off];
    ushort4 h;
    h.x = f2bf(v.x); h.y = f2bf(v.y); h.z = f2bf(v.z); h.w = f2bf(v.w);
    *(ushort4*)&Xb[off] = h;
    s0 += v.x; s1 += v.y; s2 += v.z; s3 += v.w;
  }
  atomicAdd(&xsum[c * 4 + 0], s0);
  atomicAdd(&xsum[c * 4 + 1], s1);
  atomicAdd(&xsum[c * 4 + 2], s2);
  atomicAdd(&xsum[c * 4 + 3], s3);
}

// ---- K2: convert + transpose W -> Wbt bf16 [n][k] ----
__global__ __launch_bounds__(256) void convw_kernel(const float* __restrict__ W,
                                                    u16* __restrict__ Wbt) {
  __shared__ __align__(16) u16 t[64][72];  // pad 8 keeps 16B alignment (72*2=144=16*9)
  const int tid = threadIdx.x;
  const int n0 = blockIdx.x * 64, k0 = blockIdx.y * 64;
  const int rb = tid >> 4, c4 = tid & 15;
#pragma unroll
  for (int i = 0; i < 4; ++i) {
    int r = rb + i * 16;  // k-row within tile
    const float4 v = *(const float4*)&W[(size_t)(k0 + r) * H + n0 + c4 * 4];
    t[c4 * 4 + 0][r] = f2bf(v.x);
    t[c4 * 4 + 1][r] = f2bf(v.y);
    t[c4 * 4 + 2][r] = f2bf(v.z);
    t[c4 * 4 + 3][r] = f2bf(v.w);
  }
  __syncthreads();
  const int seg = tid & 7;
#pragma unroll
  for (int p = 0; p < 2; ++p) {
    int wr = p * 32 + (tid >> 3);
    *(u16x8*)&Wbt[(size_t)(n0 + wr) * H + k0 + seg * 8] = *(const u16x8*)&t[wr][seg * 8];
  }
}

// ---- K3: output = (x @ W) * meta, bf16 MFMA, m97 structure ----
// 128x128 tile, BK=32, global_load_lds width=16, 4 waves, 4x4 frags of 16x16x32
__global__ __launch_bounds__(256) void gemm2_kernel(const u16* __restrict__ Xb,
                                                    const u16* __restrict__ Wbt,
                                                    const float* __restrict__ meta,
                                                    float* __restrict__ out) {
  __shared__ __align__(16) u16 lA[128 * 32];  // [m][k], row stride 32 elems = 64 B
  __shared__ __align__(16) u16 lB[128 * 32];  // [n][k]

  const int tid = threadIdx.x;
  const int wave = tid >> 6;
  const int lane = tid & 63;
  const int quad = lane >> 4;
  const int l16 = lane & 15;
  const int wm = wave >> 1, wn = wave & 1;
  const size_t row0 = (size_t)blockIdx.x * 128;
  const int col0 = blockIdx.y * 128;

  // staging: lane l covers row (group + (l>>2)), elems (l&3)*8 .. +8
  const int sr = lane >> 2;
  const int sk = (lane & 3) * 8;

  f32x4 acc[4][4];
#pragma unroll
  for (int i = 0; i < 4; ++i)
#pragma unroll
    for (int j = 0; j < 4; ++j) acc[i][j] = (f32x4){0.f, 0.f, 0.f, 0.f};

  for (int k0 = 0; k0 < H; k0 += 32) {
#pragma unroll
    for (int i = 0; i < 2; ++i) {
      const int rg = i * 64 + wave * 16;  // row group base (wave-uniform)
      const u16* ga = &Xb[(row0 + rg + sr) * H + k0 + sk];
      const u16* gb = &Wbt[(size_t)(col0 + rg + sr) * H + k0 + sk];
      __builtin_amdgcn_global_load_lds((glob_uint*)ga, (lds_uint*)&lA[rg * 32], 16, 0, 0);
      __builtin_amdgcn_global_load_lds((glob_uint*)gb, (lds_uint*)&lB[rg * 32], 16, 0, 0);
    }
    __syncthreads();

    bf16x8 av[4], bv[4];
#pragma unroll
    for (int f = 0; f < 4; ++f) {
      av[f] = __builtin_bit_cast(bf16x8, *(const u16x8*)&lA[(wm * 64 + f * 16 + l16) * 32 + quad * 8]);
      bv[f] = __builtin_bit_cast(bf16x8, *(const u16x8*)&lB[(wn * 64 + f * 16 + l16) * 32 + quad * 8]);
    }
#pragma unroll
    for (int fm = 0; fm < 4; ++fm)
#pragma unroll
      for (int fn = 0; fn < 4; ++fn)
        acc[fm][fn] = __builtin_amdgcn_mfma_f32_16x16x32_bf16(av[fm], bv[fn], acc[fm][fn], 0, 0, 0);
    __syncthreads();
  }

  float mcol[4];
#pragma unroll
  for (int fn = 0; fn < 4; ++fn) mcol[fn] = meta[col0 + wn * 64 + fn * 16 + l16];
#pragma unroll
  for (int fm = 0; fm < 4; ++fm) {
#pragma unroll
    for (int fn = 0; fn < 4; ++fn) {
      int col = col0 + wn * 64 + fn * 16 + l16;
#pragma unroll
      for (int r = 0; r < 4; ++r) {
        size_t row = row0 + wm * 64 + fm * 16 + quad * 4 + r;
        out[row * H + col] = acc[fm][fn][r] * mcol[fn];
      }
    }
  }
}

// ---- fallback path (round-1 kernels, used only if ws too small) ----
__global__ __launch_bounds__(256) void colsum_kernel(const float* __restrict__ x,
                                                     float* __restrict__ xsum) {
  int col = blockIdx.x * 256 + threadIdx.x;
  size_t r0 = (size_t)blockIdx.y * 256;
  float s = 0.f;
#pragma unroll 8
  for (int r = 0; r < 256; ++r) s += x[(r0 + r) * H + col];
  atomicAdd(&xsum[col], s);
}

__global__ __launch_bounds__(256) void gemm_fallback_kernel(const float* __restrict__ X,
                                                            const float* __restrict__ W,
                                                            const float* __restrict__ meta,
                                                            float* __restrict__ out) {
  __shared__ __align__(16) u16 lA[128][40];
  __shared__ __align__(16) u16 lB[128][40];
  const int tid = threadIdx.x;
  const int wave = tid >> 6;
  const int lane = tid & 63;
  const int quad = lane >> 4;
  const int l16 = lane & 15;
  const int wm = wave >> 1, wn = wave & 1;
  const size_t row0 = (size_t)blockIdx.x * 128;
  const int col0 = blockIdx.y * 128;
  f32x4 acc[4][4];
#pragma unroll
  for (int i = 0; i < 4; ++i)
#pragma unroll
    for (int j = 0; j < 4; ++j) acc[i][j] = (f32x4){0.f, 0.f, 0.f, 0.f};
  for (int k0 = 0; k0 < H; k0 += 32) {
#pragma unroll
    for (int i = 0; i < 4; ++i) {
      int idx = i * 256 + tid;
      int r = idx >> 3, c4 = idx & 7;
      const float4 v = *(const float4*)&X[(row0 + r) * H + k0 + c4 * 4];
      ushort4 h;
      h.x = f2bf(v.x); h.y = f2bf(v.y); h.z = f2bf(v.z); h.w = f2bf(v.w);
      *(ushort4*)&lA[r][c4 * 4] = h;
    }
#pragma unroll
    for (int i = 0; i < 4; ++i) {
      int idx = i * 256 + tid;
      int kk = idx >> 5, c4 = idx & 31;
      const float4 v = *(const float4*)&W[(size_t)(k0 + kk) * H + col0 + c4 * 4];
      lB[c4 * 4 + 0][kk] = f2bf(v.x);
      lB[c4 * 4 + 1][kk] = f2bf(v.y);
      lB[c4 * 4 + 2][kk] = f2bf(v.z);
      lB[c4 * 4 + 3][kk] = f2bf(v.w);
    }
    __syncthreads();
    bf16x8 av[4], bv[4];
#pragma unroll
    for (int f = 0; f < 4; ++f) {
      av[f] = __builtin_bit_cast(bf16x8, *(const u16x8*)&lA[wm * 64 + f * 16 + l16][quad * 8]);
      bv[f] = __builtin_bit_cast(bf16x8, *(const u16x8*)&lB[wn * 64 + f * 16 + l16][quad * 8]);
    }
#pragma unroll
    for (int fm = 0; fm < 4; ++fm)
#pragma unroll
      for (int fn = 0; fn < 4; ++fn)
        acc[fm][fn] = __builtin_amdgcn_mfma_f32_16x16x32_bf16(av[fm], bv[fn], acc[fm][fn], 0, 0, 0);
    __syncthreads();
  }
  float mcol[4];
#pragma unroll
  for (int fn = 0; fn < 4; ++fn) mcol[fn] = meta[col0 + wn * 64 + fn * 16 + l16];
#pragma unroll
  for (int fm = 0; fm < 4; ++fm) {
#pragma unroll
    for (int fn = 0; fn < 4; ++fn) {
      int col = col0 + wn * 64 + fn * 16 + l16;
#pragma unroll
      for (int r = 0; r < 4; ++r) {
        size_t row = row0 + wm * 64 + fm * 16 + quad * 4 + r;
        out[row * H + col] = acc[fm][fn][r] * mcol[fn];
      }
    }
  }
}

// ---- K4: out_raw[j] = sum_k x_mean[k] * W[k][j]  (fp32, exact) ----
__global__ __launch_bounds__(256) void vecmat_kernel(const float* __restrict__ W,
                                                     const float* __restrict__ xsum,
                                                     float* __restrict__ outraw) {
  int j = blockIdx.x * 256 + threadIdx.x;
  int k0 = blockIdx.y * 64;
  float s = 0.f;
#pragma unroll 8
  for (int k = 0; k < 64; ++k) s += xsum[k0 + k] * W[(size_t)(k0 + k) * H + j];
  atomicAdd(&outraw[j], s * (1.0f / (float)BATCH));
}

// ---- K5: STDP weighted history sums ----
__global__ __launch_bounds__(256) void stdpvec_kernel(const float* __restrict__ pre,
                                                      const float* __restrict__ post,
                                                      const float* __restrict__ win,
                                                      const float* __restrict__ dec,
                                                      float* __restrict__ posv,
                                                      float* __restrict__ negh) {
  int col = blockIdx.x * 256 + threadIdx.x;
  int t0 = 1 + blockIdx.y * 20;
  float wd = win[0] * dec[0];
  float ps = 0.f, ns = 0.f;
  int tend = t0 + 20;
  if (tend > 100) tend = 100;
  for (int t = t0; t < tend; ++t) {
    float w = 0.01f * expf(-(float)(101 - t) * wd);
    ps += w * pre[t * H + col];
    if (t >= 2) ns += w * post[t * H + col];
  }
  atomicAdd(&posv[col], ps);
  atomicAdd(&negh[col], ns);
}

// ---- K6: scalars, new_meta, hist ----
__global__ __launch_bounds__(1024) void finalize_kernel(const float* __restrict__ meta,
                                                        const float* __restrict__ act,
                                                        const int* __restrict__ ptr,
                                                        const float* __restrict__ targ,
                                                        const float* __restrict__ homeo,
                                                        const float* __restrict__ mlr,
                                                        const float* __restrict__ outraw,
                                                        float* __restrict__ outmean,
                                                        float* __restrict__ scalep,
                                                        float* __restrict__ meta_out,
                                                        float* __restrict__ hist_out) {
  __shared__ float r1[16], r2[16];
  __shared__ float sc[2];
  int t = threadIdx.x;
  float om = meta[t] * outraw[t];
  outmean[t] = om;
  float a = (t < 1000) ? act[t] : 0.f;
  float s1 = om, s2 = a;
#pragma unroll
  for (int o = 32; o > 0; o >>= 1) {
    s1 += __shfl_down(s1, o, 64);
    s2 += __shfl_down(s2, o, 64);
  }
  if ((t & 63) == 0) { r1[t >> 6] = s1; r2[t >> 6] = s2; }
  __syncthreads();
  if (t == 0) {
    float ts1 = 0.f, ts2 = 0.f;
#pragma unroll
    for (int i = 0; i < 16; ++i) { ts1 += r1[i]; ts2 += r2[i]; }
    float total_mean = ts1 / (float)H;
    int p = ptr[0];
    float hist_mean = (ts2 - act[p] + total_mean) / 1000.f;
    float diff = targ[0] - hist_mean;
    sc[0] = 1.f + homeo[0] * diff;
    sc[1] = total_mean;
    scalep[0] = sc[0];
  }
  __syncthreads();
  float nm = meta[t] + mlr[0] * (om - meta[t]);
  nm = fminf(fmaxf(nm, 0.f), 2.f);
  meta_out[t] = nm;
  if (t < 1000) hist_out[t] = (t == ptr[0]) ? sc[1] : act[t];
}

// ---- K7: new_w = clip(clip(W + dW, -1,1)*scale, -1,1) ----
__global__ __launch_bounds__(256) void neww_kernel(const float* __restrict__ W,
                                                   const float* __restrict__ outmean,
                                                   const float* __restrict__ posv,
                                                   const float* __restrict__ negh,
                                                   const float* __restrict__ xsum,
                                                   const float* __restrict__ scalep,
                                                   const float* __restrict__ win,
                                                   const float* __restrict__ dec,
                                                   float* __restrict__ out) {
  int idx = blockIdx.x * 256 + threadIdx.x;
  int rr = idx >> 10;
  int cc = idx & 1023;
  float w99 = 0.01f * expf(-win[0] * dec[0]);
  float scale = scalep[0];
  float om_r = outmean[rr];
  float neg_r = negh[rr] + w99 * om_r;
  float v = W[idx] + om_r * posv[cc] - neg_r * (xsum[cc] * (1.0f / (float)BATCH));
  v = fminf(fmaxf(v, -1.f), 1.f);
  v = v * scale;
  v = fminf(fmaxf(v, -1.f), 1.f);
  out[idx] = v;
}

extern "C" void kernel_launch(void* const* d_in, const int* in_sizes, int n_in,
                              void* d_out, int out_size, void* d_ws, size_t ws_size,
                              hipStream_t stream) {
  const float* x     = (const float*)d_in[0];
  const float* W     = (const float*)d_in[1];
  const float* meta  = (const float*)d_in[2];
  const float* pre   = (const float*)d_in[3];
  const float* post  = (const float*)d_in[4];
  const float* act   = (const float*)d_in[5];
  const int*   ptr   = (const int*)d_in[6];
  const float* win   = (const float*)d_in[7];
  const float* dec   = (const float*)d_in[8];
  const float* targ  = (const float*)d_in[9];
  const float* homeo = (const float*)d_in[10];
  const float* mlr   = (const float*)d_in[11];

  float* out_y    = (float*)d_out;              // [B,H]
  float* out_w    = out_y + (size_t)BATCH * H;  // [H,H]
  float* out_meta = out_w + (size_t)H * H;      // [H]
  float* out_hist = out_meta + H;               // [1000]

  float* ws      = (float*)d_ws;
  float* xsum    = ws;          // H
  float* outraw  = ws + 1024;   // H
  float* outmean = ws + 2048;   // H
  float* posv    = ws + 3072;   // H
  float* negh    = ws + 4096;   // H
  float* scalep  = ws + 5120;   // 2
  u16* Xb  = (u16*)(ws + 6144);              // [B][H] bf16, 32 MB
  u16* Wbt = Xb + (size_t)BATCH * H;         // [H][H] bf16 transposed, 2 MB

  const size_t ws_need = 6144 * sizeof(float) + ((size_t)BATCH * H + (size_t)H * H) * sizeof(u16);

  hipMemsetAsync(d_ws, 0, 6144 * sizeof(float), stream);

  if (ws_size >= ws_need) {
    convx_kernel<<<256, 256, 0, stream>>>(x, Xb, xsum);
    convw_kernel<<<dim3(16, 16), 256, 0, stream>>>(W, Wbt);
    gemm2_kernel<<<dim3(128, 8), 256, 0, stream>>>(Xb, Wbt, meta, out_y);
  } else {
    colsum_kernel<<<dim3(4, 64), 256, 0, stream>>>(x, xsum);
    gemm_fallback_kernel<<<dim3(128, 8), 256, 0, stream>>>(x, W, meta, out_y);
  }
  vecmat_kernel<<<dim3(4, 16), 256, 0, stream>>>(W, xsum, outraw);
  stdpvec_kernel<<<dim3(4, 5), 256, 0, stream>>>(pre, post, win, dec, posv, negh);
  finalize_kernel<<<1, 1024, 0, stream>>>(meta, act, ptr, targ, homeo, mlr,
                                          outraw, outmean, scalep, out_meta, out_hist);
  neww_kernel<<<4096, 256, 0, stream>>>(W, outmean, posv, negh, xsum, scalep, win, dec, out_w);
}

// Round 3
// 224.721 us; speedup vs baseline: 1.5430x; 1.0777x over previous
//
#include <hip/hip_runtime.h>
#include <hip/hip_bf16.h>

#define H 1024
#define BATCH 16384

typedef unsigned short u16;
typedef u16 u16x8 __attribute__((ext_vector_type(8)));
typedef __bf16 bf16x8 __attribute__((ext_vector_type(8)));
typedef float f32x4 __attribute__((ext_vector_type(4)));

typedef __attribute__((address_space(3))) unsigned int lds_uint;
typedef __attribute__((address_space(1))) const unsigned int glob_uint;

__device__ __forceinline__ u16 f2bf(float f) {
  unsigned int u = __float_as_uint(f);
  u += 0x7fffu + ((u >> 16) & 1u);   // round-to-nearest-even
  return (u16)(u >> 16);
}

// ================= FAST PATH =================
// ws float offsets
#define WS_XSUMP   0                      // [256][1024] per-block col-sum partials
#define WS_XSUM    (WS_XSUMP + 256 * H)   // [1024] reduced col sums
#define WS_ORAWP   (WS_XSUM + H)          // [16][1024] vecmat partials (pre-scaled 1/B)
#define WS_POSVP   (WS_ORAWP + 16 * H)    // [5][1024]
#define WS_NEGHP   (WS_POSVP + 5 * H)     // [5][1024]
#define WS_OUTMEAN (WS_NEGHP + 5 * H)     // [1024]
#define WS_POSV    (WS_OUTMEAN + H)       // [1024]
#define WS_NEGH    (WS_POSV + H)          // [1024]
#define WS_SCALEP  (WS_NEGH + H)          // [2]
#define WS_BF16    (WS_SCALEP + 16)       // Xb then Wbt (u16), 16B-aligned

// ---- K1: prep = convx (blocks 0..255) + convw (256..511) + stdp partials (512..531)
__global__ __launch_bounds__(256) void prep_kernel(const float* __restrict__ X,
                                                   const float* __restrict__ W,
                                                   u16* __restrict__ Xb,
                                                   u16* __restrict__ Wbt,
                                                   float* __restrict__ ws,
                                                   const float* __restrict__ pre,
                                                   const float* __restrict__ post,
                                                   const float* __restrict__ win,
                                                   const float* __restrict__ dec) {
  __shared__ __align__(16) u16 t[64][72];
  const int b = blockIdx.x, tid = threadIdx.x;
  if (b < 256) {
    // --- convert X fp32->bf16, per-block column partial sums (no atomics) ---
    size_t r0 = (size_t)b * 64;
    float s0 = 0.f, s1 = 0.f, s2 = 0.f, s3 = 0.f;
#pragma unroll 4
    for (int r = 0; r < 64; ++r) {
      size_t off = (r0 + r) * H + tid * 4;
      const float4 v = *(const float4*)&X[off];
      ushort4 h;
      h.x = f2bf(v.x); h.y = f2bf(v.y); h.z = f2bf(v.z); h.w = f2bf(v.w);
      *(ushort4*)&Xb[off] = h;
      s0 += v.x; s1 += v.y; s2 += v.z; s3 += v.w;
    }
    float* row = &ws[WS_XSUMP + b * H];
    row[tid * 4 + 0] = s0; row[tid * 4 + 1] = s1;
    row[tid * 4 + 2] = s2; row[tid * 4 + 3] = s3;
  } else if (b < 512) {
    // --- convert + transpose W -> Wbt bf16 [n][k] ---
    const int b2 = b - 256;
    const int n0 = (b2 & 15) * 64, k0 = (b2 >> 4) * 64;
    const int rb = tid >> 4, c4 = tid & 15;
#pragma unroll
    for (int i = 0; i < 4; ++i) {
      int r = rb + i * 16;
      const float4 v = *(const float4*)&W[(size_t)(k0 + r) * H + n0 + c4 * 4];
      t[c4 * 4 + 0][r] = f2bf(v.x);
      t[c4 * 4 + 1][r] = f2bf(v.y);
      t[c4 * 4 + 2][r] = f2bf(v.z);
      t[c4 * 4 + 3][r] = f2bf(v.w);
    }
    __syncthreads();
    const int seg = tid & 7;
#pragma unroll
    for (int p = 0; p < 2; ++p) {
      int wr = p * 32 + (tid >> 3);
      *(u16x8*)&Wbt[(size_t)(n0 + wr) * H + k0 + seg * 8] = *(const u16x8*)&t[wr][seg * 8];
    }
  } else {
    // --- STDP weighted history partials (no atomics) ---
    const int b2 = b - 512;               // 0..19
    const int col = (b2 & 3) * 256 + tid;
    const int seg = b2 >> 2;              // 0..4
    const int t0 = 1 + seg * 20;
    int tend = t0 + 20; if (tend > 100) tend = 100;
    float wd = win[0] * dec[0];
    float ps = 0.f, ns = 0.f;
    for (int tt = t0; tt < tend; ++tt) {
      float w = 0.01f * expf(-(float)(101 - tt) * wd);
      ps += w * pre[tt * H + col];
      if (tt >= 2) ns += w * post[tt * H + col];
    }
    ws[WS_POSVP + seg * H + col] = ps;
    ws[WS_NEGHP + seg * H + col] = ns;
  }
}

// ---- K2: blocks 0..63 = vecmat (reduce xsum + outraw partials); 64..1087 = GEMM
// GEMM: 128x128 tile, BK=64 (two ks halves, LDS [ks][128][32]), global_load_lds w=16
__global__ __launch_bounds__(256) void gemm_vm_kernel(const u16* __restrict__ Xb,
                                                      const u16* __restrict__ Wbt,
                                                      const float* __restrict__ meta,
                                                      const float* __restrict__ W,
                                                      float* __restrict__ ws,
                                                      float* __restrict__ out) {
  __shared__ __align__(16) u16 lA[8192];  // 16 KB: [ks][128][32]
  __shared__ __align__(16) u16 lB[8192];
  __shared__ float xs[64];

  const int b = blockIdx.x, tid = threadIdx.x;

  if (b < 64) {
    // --- vecmat: out_raw[j] = (1/B) * sum_k xsum[k] * W[k][j] over k-chunk ---
    const int jx = b & 3, ky = b >> 2;
    if (tid < 64) {
      float s = 0.f;
      const float* p = &ws[WS_XSUMP + ky * 64 + tid];
#pragma unroll 8
      for (int q = 0; q < 256; ++q) s += p[q * H];
      xs[tid] = s;
      if (jx == 0) ws[WS_XSUM + ky * 64 + tid] = s;
    }
    __syncthreads();
    const int j = jx * 256 + tid;
    float s = 0.f;
#pragma unroll 8
    for (int k = 0; k < 64; ++k) s += xs[k] * W[(size_t)(ky * 64 + k) * H + j];
    ws[WS_ORAWP + ky * H + j] = s * (1.0f / (float)BATCH);
    return;
  }

  const int bg = b - 64;
  const int mt = bg & 127, nt = bg >> 7;
  const size_t row0 = (size_t)mt * 128;
  const int col0 = nt * 128;
  const int wave = tid >> 6;
  const int lane = tid & 63;
  const int quad = lane >> 4;
  const int l16 = lane & 15;
  const int wm = wave >> 1, wn = wave & 1;

  f32x4 acc[4][4];
#pragma unroll
  for (int i = 0; i < 4; ++i)
#pragma unroll
    for (int j = 0; j < 4; ++j) acc[i][j] = (f32x4){0.f, 0.f, 0.f, 0.f};

  for (int k0 = 0; k0 < H; k0 += 64) {
#pragma unroll
    for (int i = 0; i < 4; ++i) {
      const int c = wave * 4 + i;          // chunk 0..15 (wave-uniform)
      const int half = c >> 3;             // ks half
      const int rr = (c & 7) * 16 + (lane >> 2);
      const int kk = half * 32 + (lane & 3) * 8;
      const u16* ga = &Xb[(row0 + rr) * H + k0 + kk];
      const u16* gb = &Wbt[(size_t)(col0 + rr) * H + k0 + kk];
      u16* la = &lA[half * 4096 + (c & 7) * 512];
      u16* lb = &lB[half * 4096 + (c & 7) * 512];
      __builtin_amdgcn_global_load_lds((glob_uint*)ga, (lds_uint*)la, 16, 0, 0);
      __builtin_amdgcn_global_load_lds((glob_uint*)gb, (lds_uint*)lb, 16, 0, 0);
    }
    __syncthreads();
#pragma unroll
    for (int ks = 0; ks < 2; ++ks) {
      bf16x8 av[4], bv[4];
#pragma unroll
      for (int f = 0; f < 4; ++f) {
        av[f] = __builtin_bit_cast(bf16x8,
            *(const u16x8*)&lA[ks * 4096 + (wm * 64 + f * 16 + l16) * 32 + quad * 8]);
        bv[f] = __builtin_bit_cast(bf16x8,
            *(const u16x8*)&lB[ks * 4096 + (wn * 64 + f * 16 + l16) * 32 + quad * 8]);
      }
#pragma unroll
      for (int fm = 0; fm < 4; ++fm)
#pragma unroll
        for (int fn = 0; fn < 4; ++fn)
          acc[fm][fn] = __builtin_amdgcn_mfma_f32_16x16x32_bf16(av[fm], bv[fn], acc[fm][fn], 0, 0, 0);
    }
    __syncthreads();
  }

  float mcol[4];
#pragma unroll
  for (int fn = 0; fn < 4; ++fn) mcol[fn] = meta[col0 + wn * 64 + fn * 16 + l16];
#pragma unroll
  for (int fm = 0; fm < 4; ++fm) {
#pragma unroll
    for (int fn = 0; fn < 4; ++fn) {
      int col = col0 + wn * 64 + fn * 16 + l16;
#pragma unroll
      for (int r = 0; r < 4; ++r) {
        size_t row = row0 + wm * 64 + fm * 16 + quad * 4 + r;
        out[row * H + col] = acc[fm][fn][r] * mcol[fn];
      }
    }
  }
}

// ---- K3: reduce partials, scalars, new_meta, hist ----
__global__ __launch_bounds__(1024) void finalize2_kernel(const float* __restrict__ meta,
                                                         const float* __restrict__ act,
                                                         const int* __restrict__ ptr,
                                                         const float* __restrict__ targ,
                                                         const float* __restrict__ homeo,
                                                         const float* __restrict__ mlr,
                                                         float* __restrict__ ws,
                                                         float* __restrict__ meta_out,
                                                         float* __restrict__ hist_out) {
  __shared__ float r1[16], r2[16];
  __shared__ float sc[2];
  int t = threadIdx.x;
  float oraw = 0.f;
#pragma unroll
  for (int i = 0; i < 16; ++i) oraw += ws[WS_ORAWP + i * H + t];
  float om = meta[t] * oraw;
  ws[WS_OUTMEAN + t] = om;
  float pv = 0.f, nv = 0.f;
#pragma unroll
  for (int i = 0; i < 5; ++i) { pv += ws[WS_POSVP + i * H + t]; nv += ws[WS_NEGHP + i * H + t]; }
  ws[WS_POSV + t] = pv;
  ws[WS_NEGH + t] = nv;

  float a = (t < 1000) ? act[t] : 0.f;
  float s1 = om, s2 = a;
#pragma unroll
  for (int o = 32; o > 0; o >>= 1) {
    s1 += __shfl_down(s1, o, 64);
    s2 += __shfl_down(s2, o, 64);
  }
  if ((t & 63) == 0) { r1[t >> 6] = s1; r2[t >> 6] = s2; }
  __syncthreads();
  if (t == 0) {
    float ts1 = 0.f, ts2 = 0.f;
#pragma unroll
    for (int i = 0; i < 16; ++i) { ts1 += r1[i]; ts2 += r2[i]; }
    float total_mean = ts1 / (float)H;
    int p = ptr[0];
    float hist_mean = (ts2 - act[p] + total_mean) / 1000.f;
    float diff = targ[0] - hist_mean;
    sc[0] = 1.f + homeo[0] * diff;
    sc[1] = total_mean;
    ws[WS_SCALEP] = sc[0];
  }
  __syncthreads();
  float nm = meta[t] + mlr[0] * (om - meta[t]);
  nm = fminf(fmaxf(nm, 0.f), 2.f);
  meta_out[t] = nm;
  if (t < 1000) hist_out[t] = (t == ptr[0]) ? sc[1] : act[t];
}

// ---- K4: new_w = clip(clip(W + dW, -1,1)*scale, -1,1), float4 ----
__global__ __launch_bounds__(256) void neww_kernel(const float* __restrict__ W,
                                                   const float* __restrict__ outmean,
                                                   const float* __restrict__ posv,
                                                   const float* __restrict__ negh,
                                                   const float* __restrict__ xsum,
                                                   const float* __restrict__ scalep,
                                                   const float* __restrict__ win,
                                                   const float* __restrict__ dec,
                                                   float* __restrict__ out) {
  int idx4 = blockIdx.x * 256 + threadIdx.x;  // 0..262143
  int rr = idx4 >> 8;
  int c4 = (idx4 & 255) * 4;
  float w99 = 0.01f * expf(-win[0] * dec[0]);
  float scale = scalep[0];
  float om_r = outmean[rr];
  float neg_r = negh[rr] + w99 * om_r;
  const float4 wv = *(const float4*)&W[(size_t)rr * H + c4];
  const float4 pv = *(const float4*)&posv[c4];
  const float4 xv = *(const float4*)&xsum[c4];
  float4 o;
  float vx[4] = {wv.x, wv.y, wv.z, wv.w};
  float px[4] = {pv.x, pv.y, pv.z, pv.w};
  float xx[4] = {xv.x, xv.y, xv.z, xv.w};
  float ox[4];
#pragma unroll
  for (int i = 0; i < 4; ++i) {
    float v = vx[i] + om_r * px[i] - neg_r * (xx[i] * (1.0f / (float)BATCH));
    v = fminf(fmaxf(v, -1.f), 1.f);
    v = v * scale;
    ox[i] = fminf(fmaxf(v, -1.f), 1.f);
  }
  o.x = ox[0]; o.y = ox[1]; o.z = ox[2]; o.w = ox[3];
  *(float4*)&out[(size_t)rr * H + c4] = o;
}

// ================= LEGACY FALLBACK (small ws) =================
__global__ __launch_bounds__(256) void colsum_kernel(const float* __restrict__ x,
                                                     float* __restrict__ xsum) {
  int col = blockIdx.x * 256 + threadIdx.x;
  size_t r0 = (size_t)blockIdx.y * 256;
  float s = 0.f;
#pragma unroll 8
  for (int r = 0; r < 256; ++r) s += x[(r0 + r) * H + col];
  atomicAdd(&xsum[col], s);
}

__global__ __launch_bounds__(256) void gemm_fallback_kernel(const float* __restrict__ X,
                                                            const float* __restrict__ W,
                                                            const float* __restrict__ meta,
                                                            float* __restrict__ out) {
  __shared__ __align__(16) u16 lA[128][40];
  __shared__ __align__(16) u16 lB[128][40];
  const int tid = threadIdx.x;
  const int wave = tid >> 6;
  const int lane = tid & 63;
  const int quad = lane >> 4;
  const int l16 = lane & 15;
  const int wm = wave >> 1, wn = wave & 1;
  const size_t row0 = (size_t)blockIdx.x * 128;
  const int col0 = blockIdx.y * 128;
  f32x4 acc[4][4];
#pragma unroll
  for (int i = 0; i < 4; ++i)
#pragma unroll
    for (int j = 0; j < 4; ++j) acc[i][j] = (f32x4){0.f, 0.f, 0.f, 0.f};
  for (int k0 = 0; k0 < H; k0 += 32) {
#pragma unroll
    for (int i = 0; i < 4; ++i) {
      int idx = i * 256 + tid;
      int r = idx >> 3, c4 = idx & 7;
      const float4 v = *(const float4*)&X[(row0 + r) * H + k0 + c4 * 4];
      ushort4 h;
      h.x = f2bf(v.x); h.y = f2bf(v.y); h.z = f2bf(v.z); h.w = f2bf(v.w);
      *(ushort4*)&lA[r][c4 * 4] = h;
    }
#pragma unroll
    for (int i = 0; i < 4; ++i) {
      int idx = i * 256 + tid;
      int kk = idx >> 5, c4 = idx & 31;
      const float4 v = *(const float4*)&W[(size_t)(k0 + kk) * H + col0 + c4 * 4];
      lB[c4 * 4 + 0][kk] = f2bf(v.x);
      lB[c4 * 4 + 1][kk] = f2bf(v.y);
      lB[c4 * 4 + 2][kk] = f2bf(v.z);
      lB[c4 * 4 + 3][kk] = f2bf(v.w);
    }
    __syncthreads();
    bf16x8 av[4], bv[4];
#pragma unroll
    for (int f = 0; f < 4; ++f) {
      av[f] = __builtin_bit_cast(bf16x8, *(const u16x8*)&lA[wm * 64 + f * 16 + l16][quad * 8]);
      bv[f] = __builtin_bit_cast(bf16x8, *(const u16x8*)&lB[wn * 64 + f * 16 + l16][quad * 8]);
    }
#pragma unroll
    for (int fm = 0; fm < 4; ++fm)
#pragma unroll
      for (int fn = 0; fn < 4; ++fn)
        acc[fm][fn] = __builtin_amdgcn_mfma_f32_16x16x32_bf16(av[fm], bv[fn], acc[fm][fn], 0, 0, 0);
    __syncthreads();
  }
  float mcol[4];
#pragma unroll
  for (int fn = 0; fn < 4; ++fn) mcol[fn] = meta[col0 + wn * 64 + fn * 16 + l16];
#pragma unroll
  for (int fm = 0; fm < 4; ++fm) {
#pragma unroll
    for (int fn = 0; fn < 4; ++fn) {
      int col = col0 + wn * 64 + fn * 16 + l16;
#pragma unroll
      for (int r = 0; r < 4; ++r) {
        size_t row = row0 + wm * 64 + fm * 16 + quad * 4 + r;
        out[row * H + col] = acc[fm][fn][r] * mcol[fn];
      }
    }
  }
}

__global__ __launch_bounds__(256) void vecmat_kernel(const float* __restrict__ W,
                                                     const float* __restrict__ xsum,
                                                     float* __restrict__ outraw) {
  int j = blockIdx.x * 256 + threadIdx.x;
  int k0 = blockIdx.y * 64;
  float s = 0.f;
#pragma unroll 8
  for (int k = 0; k < 64; ++k) s += xsum[k0 + k] * W[(size_t)(k0 + k) * H + j];
  atomicAdd(&outraw[j], s * (1.0f / (float)BATCH));
}

__global__ __launch_bounds__(256) void stdpvec_kernel(const float* __restrict__ pre,
                                                      const float* __restrict__ post,
                                                      const float* __restrict__ win,
                                                      const float* __restrict__ dec,
                                                      float* __restrict__ posv,
                                                      float* __restrict__ negh) {
  int col = blockIdx.x * 256 + threadIdx.x;
  int t0 = 1 + blockIdx.y * 20;
  float wd = win[0] * dec[0];
  float ps = 0.f, ns = 0.f;
  int tend = t0 + 20;
  if (tend > 100) tend = 100;
  for (int t = t0; t < tend; ++t) {
    float w = 0.01f * expf(-(float)(101 - t) * wd);
    ps += w * pre[t * H + col];
    if (t >= 2) ns += w * post[t * H + col];
  }
  atomicAdd(&posv[col], ps);
  atomicAdd(&negh[col], ns);
}

__global__ __launch_bounds__(1024) void finalize_kernel(const float* __restrict__ meta,
                                                        const float* __restrict__ act,
                                                        const int* __restrict__ ptr,
                                                        const float* __restrict__ targ,
                                                        const float* __restrict__ homeo,
                                                        const float* __restrict__ mlr,
                                                        const float* __restrict__ outraw,
                                                        float* __restrict__ outmean,
                                                        float* __restrict__ scalep,
                                                        float* __restrict__ meta_out,
                                                        float* __restrict__ hist_out) {
  __shared__ float r1[16], r2[16];
  __shared__ float sc[2];
  int t = threadIdx.x;
  float om = meta[t] * outraw[t];
  outmean[t] = om;
  float a = (t < 1000) ? act[t] : 0.f;
  float s1 = om, s2 = a;
#pragma unroll
  for (int o = 32; o > 0; o >>= 1) {
    s1 += __shfl_down(s1, o, 64);
    s2 += __shfl_down(s2, o, 64);
  }
  if ((t & 63) == 0) { r1[t >> 6] = s1; r2[t >> 6] = s2; }
  __syncthreads();
  if (t == 0) {
    float ts1 = 0.f, ts2 = 0.f;
#pragma unroll
    for (int i = 0; i < 16; ++i) { ts1 += r1[i]; ts2 += r2[i]; }
    float total_mean = ts1 / (float)H;
    int p = ptr[0];
    float hist_mean = (ts2 - act[p] + total_mean) / 1000.f;
    float diff = targ[0] - hist_mean;
    sc[0] = 1.f + homeo[0] * diff;
    sc[1] = total_mean;
    scalep[0] = sc[0];
  }
  __syncthreads();
  float nm = meta[t] + mlr[0] * (om - meta[t]);
  nm = fminf(fmaxf(nm, 0.f), 2.f);
  meta_out[t] = nm;
  if (t < 1000) hist_out[t] = (t == ptr[0]) ? sc[1] : act[t];
}

extern "C" void kernel_launch(void* const* d_in, const int* in_sizes, int n_in,
                              void* d_out, int out_size, void* d_ws, size_t ws_size,
                              hipStream_t stream) {
  const float* x     = (const float*)d_in[0];
  const float* W     = (const float*)d_in[1];
  const float* meta  = (const float*)d_in[2];
  const float* pre   = (const float*)d_in[3];
  const float* post  = (const float*)d_in[4];
  const float* act   = (const float*)d_in[5];
  const int*   ptr   = (const int*)d_in[6];
  const float* win   = (const float*)d_in[7];
  const float* dec   = (const float*)d_in[8];
  const float* targ  = (const float*)d_in[9];
  const float* homeo = (const float*)d_in[10];
  const float* mlr   = (const float*)d_in[11];

  float* out_y    = (float*)d_out;              // [B,H]
  float* out_w    = out_y + (size_t)BATCH * H;  // [H,H]
  float* out_meta = out_w + (size_t)H * H;      // [H]
  float* out_hist = out_meta + H;               // [1000]

  float* ws = (float*)d_ws;
  u16* Xb  = (u16*)(ws + WS_BF16);       // [B][H] bf16, 32 MB
  u16* Wbt = Xb + (size_t)BATCH * H;     // [H][H] bf16 transposed, 2 MB

  const size_t ws_need = (size_t)WS_BF16 * sizeof(float) +
                         ((size_t)BATCH * H + (size_t)H * H) * sizeof(u16);

  if (ws_size >= ws_need) {
    // fast path: 4 dispatches, no memset, no atomics
    prep_kernel<<<532, 256, 0, stream>>>(x, W, Xb, Wbt, ws, pre, post, win, dec);
    gemm_vm_kernel<<<1088, 256, 0, stream>>>(Xb, Wbt, meta, W, ws, out_y);
    finalize2_kernel<<<1, 1024, 0, stream>>>(meta, act, ptr, targ, homeo, mlr,
                                             ws, out_meta, out_hist);
    neww_kernel<<<1024, 256, 0, stream>>>(W, ws + WS_OUTMEAN, ws + WS_POSV, ws + WS_NEGH,
                                          ws + WS_XSUM, ws + WS_SCALEP, win, dec, out_w);
  } else {
    // legacy path (atomics, fp32 gemm)
    float* xsum    = ws;
    float* outraw  = ws + 1024;
    float* outmean = ws + 2048;
    float* posv    = ws + 3072;
    float* negh    = ws + 4096;
    float* scalep  = ws + 5120;
    hipMemsetAsync(d_ws, 0, 6144 * sizeof(float), stream);
    colsum_kernel<<<dim3(4, 64), 256, 0, stream>>>(x, xsum);
    gemm_fallback_kernel<<<dim3(128, 8), 256, 0, stream>>>(x, W, meta, out_y);
    vecmat_kernel<<<dim3(4, 16), 256, 0, stream>>>(W, xsum, outraw);
    stdpvec_kernel<<<dim3(4, 5), 256, 0, stream>>>(pre, post, win, dec, posv, negh);
    finalize_kernel<<<1, 1024, 0, stream>>>(meta, act, ptr, targ, homeo, mlr,
                                            outraw, outmean, scalep, out_meta, out_hist);
    neww_kernel<<<1024, 256, 0, stream>>>(W, outmean, posv, negh, xsum, scalep, win, dec, out_w);
  }
}

// Round 4
// 214.931 us; speedup vs baseline: 1.6133x; 1.0455x over previous
//
#include <hip/hip_runtime.h>
#include <hip/hip_bf16.h>

#define H 1024
#define BATCH 16384

typedef unsigned short u16;
typedef u16 u16x8 __attribute__((ext_vector_type(8)));
typedef __bf16 bf16x8 __attribute__((ext_vector_type(8)));
typedef float f32x4 __attribute__((ext_vector_type(4)));

typedef __attribute__((address_space(3))) unsigned int lds_uint;
typedef __attribute__((address_space(1))) const unsigned int glob_uint;

__device__ __forceinline__ u16 f2bf(float f) {
  unsigned int u = __float_as_uint(f);
  u += 0x7fffu + ((u >> 16) & 1u);   // round-to-nearest-even
  return (u16)(u >> 16);
}

// ================= FAST PATH =================
// ws float offsets
#define WS_XSUMP   0                      // [256][1024] per-block col-sum partials
#define WS_XSUM    (WS_XSUMP + 256 * H)   // [1024] reduced col sums
#define WS_ORAWP   (WS_XSUM + H)          // [16][1024] vecmat partials (pre-scaled 1/B)
#define WS_POSVP   (WS_ORAWP + 16 * H)    // [5][1024]
#define WS_NEGHP   (WS_POSVP + 5 * H)     // [5][1024]
#define WS_SCRATCH (WS_NEGHP + 5 * H)     // unused spare
#define WS_BF16    (WS_SCRATCH + 16)      // Xb then Wbt (u16), 16B-aligned

// ---- K1: prep = convx (blocks 0..255) + convw (256..511) + stdp partials (512..531)
__global__ __launch_bounds__(256) void prep_kernel(const float* __restrict__ X,
                                                   const float* __restrict__ W,
                                                   u16* __restrict__ Xb,
                                                   u16* __restrict__ Wbt,
                                                   float* __restrict__ ws,
                                                   const float* __restrict__ pre,
                                                   const float* __restrict__ post,
                                                   const float* __restrict__ win,
                                                   const float* __restrict__ dec) {
  __shared__ __align__(16) u16 t[64][72];
  const int b = blockIdx.x, tid = threadIdx.x;
  if (b < 256) {
    // --- convert X fp32->bf16, per-block column partial sums (no atomics) ---
    size_t r0 = (size_t)b * 64;
    float s0 = 0.f, s1 = 0.f, s2 = 0.f, s3 = 0.f;
#pragma unroll 4
    for (int r = 0; r < 64; ++r) {
      size_t off = (r0 + r) * H + tid * 4;
      const float4 v = *(const float4*)&X[off];
      ushort4 h;
      h.x = f2bf(v.x); h.y = f2bf(v.y); h.z = f2bf(v.z); h.w = f2bf(v.w);
      *(ushort4*)&Xb[off] = h;
      s0 += v.x; s1 += v.y; s2 += v.z; s3 += v.w;
    }
    float* row = &ws[WS_XSUMP + b * H];
    row[tid * 4 + 0] = s0; row[tid * 4 + 1] = s1;
    row[tid * 4 + 2] = s2; row[tid * 4 + 3] = s3;
  } else if (b < 512) {
    // --- convert + transpose W -> Wbt bf16 [n][k] ---
    const int b2 = b - 256;
    const int n0 = (b2 & 15) * 64, k0 = (b2 >> 4) * 64;
    const int rb = tid >> 4, c4 = tid & 15;
#pragma unroll
    for (int i = 0; i < 4; ++i) {
      int r = rb + i * 16;
      const float4 v = *(const float4*)&W[(size_t)(k0 + r) * H + n0 + c4 * 4];
      t[c4 * 4 + 0][r] = f2bf(v.x);
      t[c4 * 4 + 1][r] = f2bf(v.y);
      t[c4 * 4 + 2][r] = f2bf(v.z);
      t[c4 * 4 + 3][r] = f2bf(v.w);
    }
    __syncthreads();
    const int seg = tid & 7;
#pragma unroll
    for (int p = 0; p < 2; ++p) {
      int wr = p * 32 + (tid >> 3);
      *(u16x8*)&Wbt[(size_t)(n0 + wr) * H + k0 + seg * 8] = *(const u16x8*)&t[wr][seg * 8];
    }
  } else {
    // --- STDP weighted history partials (no atomics) ---
    const int b2 = b - 512;               // 0..19
    const int col = (b2 & 3) * 256 + tid;
    const int seg = b2 >> 2;              // 0..4
    const int t0 = 1 + seg * 20;
    int tend = t0 + 20; if (tend > 100) tend = 100;
    float wd = win[0] * dec[0];
    float ps = 0.f, ns = 0.f;
    for (int tt = t0; tt < tend; ++tt) {
      float w = 0.01f * expf(-(float)(101 - tt) * wd);
      ps += w * pre[tt * H + col];
      if (tt >= 2) ns += w * post[tt * H + col];
    }
    ws[WS_POSVP + seg * H + col] = ps;
    ws[WS_NEGHP + seg * H + col] = ns;
  }
}

// ---- K2: blocks 0..63 = vecmat (reduce xsum + outraw partials); 64..1087 = GEMM
// GEMM: 128x128 tile, BK=32 (round-2 config: 16 KB LDS), global_load_lds w=16
__global__ __launch_bounds__(256) void gemm_vm_kernel(const u16* __restrict__ Xb,
                                                      const u16* __restrict__ Wbt,
                                                      const float* __restrict__ meta,
                                                      const float* __restrict__ W,
                                                      float* __restrict__ ws,
                                                      float* __restrict__ out) {
  __shared__ __align__(16) u16 lA[128 * 32];  // 8 KB: [m][k]
  __shared__ __align__(16) u16 lB[128 * 32];  // 8 KB: [n][k]
  __shared__ float xs[64];

  const int b = blockIdx.x, tid = threadIdx.x;

  if (b < 64) {
    // --- vecmat: out_raw[j] = (1/B) * sum_k xsum[k] * W[k][j] over k-chunk ---
    const int jx = b & 3, ky = b >> 2;
    if (tid < 64) {
      float s = 0.f;
      const float* p = &ws[WS_XSUMP + ky * 64 + tid];
#pragma unroll 8
      for (int q = 0; q < 256; ++q) s += p[q * H];
      xs[tid] = s;
      if (jx == 0) ws[WS_XSUM + ky * 64 + tid] = s;
    }
    __syncthreads();
    const int j = jx * 256 + tid;
    float s = 0.f;
#pragma unroll 8
    for (int k = 0; k < 64; ++k) s += xs[k] * W[(size_t)(ky * 64 + k) * H + j];
    ws[WS_ORAWP + ky * H + j] = s * (1.0f / (float)BATCH);
    return;
  }

  const int bg = b - 64;
  const int mt = bg & 127, nt = bg >> 7;
  const size_t row0 = (size_t)mt * 128;
  const int col0 = nt * 128;
  const int wave = tid >> 6;
  const int lane = tid & 63;
  const int quad = lane >> 4;
  const int l16 = lane & 15;
  const int wm = wave >> 1, wn = wave & 1;

  const int sr = lane >> 2;
  const int sk = (lane & 3) * 8;

  f32x4 acc[4][4];
#pragma unroll
  for (int i = 0; i < 4; ++i)
#pragma unroll
    for (int j = 0; j < 4; ++j) acc[i][j] = (f32x4){0.f, 0.f, 0.f, 0.f};

  for (int k0 = 0; k0 < H; k0 += 32) {
#pragma unroll
    for (int i = 0; i < 2; ++i) {
      const int rg = i * 64 + wave * 16;  // wave-uniform row group
      const u16* ga = &Xb[(row0 + rg + sr) * H + k0 + sk];
      const u16* gb = &Wbt[(size_t)(col0 + rg + sr) * H + k0 + sk];
      __builtin_amdgcn_global_load_lds((glob_uint*)ga, (lds_uint*)&lA[rg * 32], 16, 0, 0);
      __builtin_amdgcn_global_load_lds((glob_uint*)gb, (lds_uint*)&lB[rg * 32], 16, 0, 0);
    }
    __syncthreads();

    bf16x8 av[4], bv[4];
#pragma unroll
    for (int f = 0; f < 4; ++f) {
      av[f] = __builtin_bit_cast(bf16x8, *(const u16x8*)&lA[(wm * 64 + f * 16 + l16) * 32 + quad * 8]);
      bv[f] = __builtin_bit_cast(bf16x8, *(const u16x8*)&lB[(wn * 64 + f * 16 + l16) * 32 + quad * 8]);
    }
#pragma unroll
    for (int fm = 0; fm < 4; ++fm)
#pragma unroll
      for (int fn = 0; fn < 4; ++fn)
        acc[fm][fn] = __builtin_amdgcn_mfma_f32_16x16x32_bf16(av[fm], bv[fn], acc[fm][fn], 0, 0, 0);
    __syncthreads();
  }

  float mcol[4];
#pragma unroll
  for (int fn = 0; fn < 4; ++fn) mcol[fn] = meta[col0 + wn * 64 + fn * 16 + l16];
#pragma unroll
  for (int fm = 0; fm < 4; ++fm) {
#pragma unroll
    for (int fn = 0; fn < 4; ++fn) {
      int col = col0 + wn * 64 + fn * 16 + l16;
#pragma unroll
      for (int r = 0; r < 4; ++r) {
        size_t row = row0 + wm * 64 + fm * 16 + quad * 4 + r;
        out[row * H + col] = acc[fm][fn][r] * mcol[fn];
      }
    }
  }
}

// ---- K3: tail = finalize + new_w fused. 1024 blocks, one W-row each.
// Every block redundantly recomputes the global scalars from the small
// partial arrays (all L2/L3-resident) -> identical fp32 results, no dispatch.
__global__ __launch_bounds__(256) void tail_kernel(const float* __restrict__ W,
                                                   const float* __restrict__ meta,
                                                   const float* __restrict__ act,
                                                   const int* __restrict__ ptr,
                                                   const float* __restrict__ targ,
                                                   const float* __restrict__ homeo,
                                                   const float* __restrict__ mlr,
                                                   const float* __restrict__ win,
                                                   const float* __restrict__ dec,
                                                   const float* __restrict__ ws,
                                                   float* __restrict__ out_w,
                                                   float* __restrict__ meta_out,
                                                   float* __restrict__ hist_out) {
  __shared__ float r1[4], r2[4];
  const int r = blockIdx.x;        // W row
  const int t = threadIdx.x;
  const int c4 = t * 4;

  // --- per-thread: reduce oraw partials for 4 columns, compute om ---
  f32x4 oraw = (f32x4){0.f, 0.f, 0.f, 0.f};
#pragma unroll
  for (int i = 0; i < 16; ++i) {
    const float4 v = *(const float4*)&ws[WS_ORAWP + i * H + c4];
    oraw[0] += v.x; oraw[1] += v.y; oraw[2] += v.z; oraw[3] += v.w;
  }
  const float4 mv = *(const float4*)&meta[c4];
  f32x4 om;
  om[0] = mv.x * oraw[0]; om[1] = mv.y * oraw[1];
  om[2] = mv.z * oraw[2]; om[3] = mv.w * oraw[3];

  // --- global sums: sum(om), sum(act) ---
  float s1 = om[0] + om[1] + om[2] + om[3];
  float s2 = 0.f;
#pragma unroll
  for (int j = 0; j < 4; ++j) {
    int idx = t + j * 256;
    if (idx < 1000) s2 += act[idx];
  }
#pragma unroll
  for (int o = 32; o > 0; o >>= 1) {
    s1 += __shfl_down(s1, o, 64);
    s2 += __shfl_down(s2, o, 64);
  }
  if ((t & 63) == 0) { r1[t >> 6] = s1; r2[t >> 6] = s2; }
  __syncthreads();
  const float ts1 = r1[0] + r1[1] + r1[2] + r1[3];
  const float ts2 = r2[0] + r2[1] + r2[2] + r2[3];
  const float total_mean = ts1 / (float)H;
  const int p = ptr[0];
  const float hist_mean = (ts2 - act[p] + total_mean) / 1000.f;
  const float scale = 1.f + homeo[0] * (targ[0] - hist_mean);
  const float w99 = 0.01f * expf(-win[0] * dec[0]);

  // --- row scalars (wave-uniform loads) ---
  float oraw_r = 0.f;
#pragma unroll
  for (int i = 0; i < 16; ++i) oraw_r += ws[WS_ORAWP + i * H + r];
  const float om_r = meta[r] * oraw_r;
  float negh_r = 0.f;
#pragma unroll
  for (int i = 0; i < 5; ++i) negh_r += ws[WS_NEGHP + i * H + r];
  const float neg_r = negh_r + w99 * om_r;

  // --- per-thread column vectors: posv, xsum ---
  f32x4 pv = (f32x4){0.f, 0.f, 0.f, 0.f};
#pragma unroll
  for (int i = 0; i < 5; ++i) {
    const float4 v = *(const float4*)&ws[WS_POSVP + i * H + c4];
    pv[0] += v.x; pv[1] += v.y; pv[2] += v.z; pv[3] += v.w;
  }
  const float4 xv = *(const float4*)&ws[WS_XSUM + c4];
  float xx[4] = {xv.x, xv.y, xv.z, xv.w};
  const float4 wv = *(const float4*)&W[(size_t)r * H + c4];
  float wx[4] = {wv.x, wv.y, wv.z, wv.w};
  float4 o;
  float ox[4];
#pragma unroll
  for (int i = 0; i < 4; ++i) {
    float v = wx[i] + om_r * pv[i] - neg_r * (xx[i] * (1.0f / (float)BATCH));
    v = fminf(fmaxf(v, -1.f), 1.f);
    v = v * scale;
    ox[i] = fminf(fmaxf(v, -1.f), 1.f);
  }
  o.x = ox[0]; o.y = ox[1]; o.z = ox[2]; o.w = ox[3];
  *(float4*)&out_w[(size_t)r * H + c4] = o;

  // --- block 0: meta_out + hist_out ---
  if (r == 0) {
    float4 nm;
    float nx[4] = {mv.x, mv.y, mv.z, mv.w};
    float nr[4];
#pragma unroll
    for (int i = 0; i < 4; ++i) {
      float v = nx[i] + mlr[0] * (om[i] - nx[i]);
      nr[i] = fminf(fmaxf(v, 0.f), 2.f);
    }
    nm.x = nr[0]; nm.y = nr[1]; nm.z = nr[2]; nm.w = nr[3];
    *(float4*)&meta_out[c4] = nm;
#pragma unroll
    for (int j = 0; j < 4; ++j) {
      int idx = t + j * 256;
      if (idx < 1000) hist_out[idx] = (idx == p) ? total_mean : act[idx];
    }
  }
}

// ================= LEGACY FALLBACK (small ws) =================
__global__ __launch_bounds__(256) void colsum_kernel(const float* __restrict__ x,
                                                     float* __restrict__ xsum) {
  int col = blockIdx.x * 256 + threadIdx.x;
  size_t r0 = (size_t)blockIdx.y * 256;
  float s = 0.f;
#pragma unroll 8
  for (int r = 0; r < 256; ++r) s += x[(r0 + r) * H + col];
  atomicAdd(&xsum[col], s);
}

__global__ __launch_bounds__(256) void gemm_fallback_kernel(const float* __restrict__ X,
                                                            const float* __restrict__ W,
                                                            const float* __restrict__ meta,
                                                            float* __restrict__ out) {
  __shared__ __align__(16) u16 lA[128][40];
  __shared__ __align__(16) u16 lB[128][40];
  const int tid = threadIdx.x;
  const int wave = tid >> 6;
  const int lane = tid & 63;
  const int quad = lane >> 4;
  const int l16 = lane & 15;
  const int wm = wave >> 1, wn = wave & 1;
  const size_t row0 = (size_t)blockIdx.x * 128;
  const int col0 = blockIdx.y * 128;
  f32x4 acc[4][4];
#pragma unroll
  for (int i = 0; i < 4; ++i)
#pragma unroll
    for (int j = 0; j < 4; ++j) acc[i][j] = (f32x4){0.f, 0.f, 0.f, 0.f};
  for (int k0 = 0; k0 < H; k0 += 32) {
#pragma unroll
    for (int i = 0; i < 4; ++i) {
      int idx = i * 256 + tid;
      int r = idx >> 3, c4 = idx & 7;
      const float4 v = *(const float4*)&X[(row0 + r) * H + k0 + c4 * 4];
      ushort4 h;
      h.x = f2bf(v.x); h.y = f2bf(v.y); h.z = f2bf(v.z); h.w = f2bf(v.w);
      *(ushort4*)&lA[r][c4 * 4] = h;
    }
#pragma unroll
    for (int i = 0; i < 4; ++i) {
      int idx = i * 256 + tid;
      int kk = idx >> 5, c4 = idx & 31;
      const float4 v = *(const float4*)&W[(size_t)(k0 + kk) * H + col0 + c4 * 4];
      lB[c4 * 4 + 0][kk] = f2bf(v.x);
      lB[c4 * 4 + 1][kk] = f2bf(v.y);
      lB[c4 * 4 + 2][kk] = f2bf(v.z);
      lB[c4 * 4 + 3][kk] = f2bf(v.w);
    }
    __syncthreads();
    bf16x8 av[4], bv[4];
#pragma unroll
    for (int f = 0; f < 4; ++f) {
      av[f] = __builtin_bit_cast(bf16x8, *(const u16x8*)&lA[wm * 64 + f * 16 + l16][quad * 8]);
      bv[f] = __builtin_bit_cast(bf16x8, *(const u16x8*)&lB[wn * 64 + f * 16 + l16][quad * 8]);
    }
#pragma unroll
    for (int fm = 0; fm < 4; ++fm)
#pragma unroll
      for (int fn = 0; fn < 4; ++fn)
        acc[fm][fn] = __builtin_amdgcn_mfma_f32_16x16x32_bf16(av[fm], bv[fn], acc[fm][fn], 0, 0, 0);
    __syncthreads();
  }
  float mcol[4];
#pragma unroll
  for (int fn = 0; fn < 4; ++fn) mcol[fn] = meta[col0 + wn * 64 + fn * 16 + l16];
#pragma unroll
  for (int fm = 0; fm < 4; ++fm) {
#pragma unroll
    for (int fn = 0; fn < 4; ++fn) {
      int col = col0 + wn * 64 + fn * 16 + l16;
#pragma unroll
      for (int r = 0; r < 4; ++r) {
        size_t row = row0 + wm * 64 + fm * 16 + quad * 4 + r;
        out[row * H + col] = acc[fm][fn][r] * mcol[fn];
      }
    }
  }
}

__global__ __launch_bounds__(256) void vecmat_kernel(const float* __restrict__ W,
                                                     const float* __restrict__ xsum,
                                                     float* __restrict__ outraw) {
  int j = blockIdx.x * 256 + threadIdx.x;
  int k0 = blockIdx.y * 64;
  float s = 0.f;
#pragma unroll 8
  for (int k = 0; k < 64; ++k) s += xsum[k0 + k] * W[(size_t)(k0 + k) * H + j];
  atomicAdd(&outraw[j], s * (1.0f / (float)BATCH));
}

__global__ __launch_bounds__(256) void stdpvec_kernel(const float* __restrict__ pre,
                                                      const float* __restrict__ post,
                                                      const float* __restrict__ win,
                                                      const float* __restrict__ dec,
                                                      float* __restrict__ posv,
                                                      float* __restrict__ negh) {
  int col = blockIdx.x * 256 + threadIdx.x;
  int t0 = 1 + blockIdx.y * 20;
  float wd = win[0] * dec[0];
  float ps = 0.f, ns = 0.f;
  int tend = t0 + 20;
  if (tend > 100) tend = 100;
  for (int t = t0; t < tend; ++t) {
    float w = 0.01f * expf(-(float)(101 - t) * wd);
    ps += w * pre[t * H + col];
    if (t >= 2) ns += w * post[t * H + col];
  }
  atomicAdd(&posv[col], ps);
  atomicAdd(&negh[col], ns);
}

__global__ __launch_bounds__(1024) void finalize_kernel(const float* __restrict__ meta,
                                                        const float* __restrict__ act,
                                                        const int* __restrict__ ptr,
                                                        const float* __restrict__ targ,
                                                        const float* __restrict__ homeo,
                                                        const float* __restrict__ mlr,
                                                        const float* __restrict__ outraw,
                                                        float* __restrict__ outmean,
                                                        float* __restrict__ scalep,
                                                        float* __restrict__ meta_out,
                                                        float* __restrict__ hist_out) {
  __shared__ float r1[16], r2[16];
  __shared__ float sc[2];
  int t = threadIdx.x;
  float om = meta[t] * outraw[t];
  outmean[t] = om;
  float a = (t < 1000) ? act[t] : 0.f;
  float s1 = om, s2 = a;
#pragma unroll
  for (int o = 32; o > 0; o >>= 1) {
    s1 += __shfl_down(s1, o, 64);
    s2 += __shfl_down(s2, o, 64);
  }
  if ((t & 63) == 0) { r1[t >> 6] = s1; r2[t >> 6] = s2; }
  __syncthreads();
  if (t == 0) {
    float ts1 = 0.f, ts2 = 0.f;
#pragma unroll
    for (int i = 0; i < 16; ++i) { ts1 += r1[i]; ts2 += r2[i]; }
    float total_mean = ts1 / (float)H;
    int p = ptr[0];
    float hist_mean = (ts2 - act[p] + total_mean) / 1000.f;
    float diff = targ[0] - hist_mean;
    sc[0] = 1.f + homeo[0] * diff;
    sc[1] = total_mean;
    scalep[0] = sc[0];
  }
  __syncthreads();
  float nm = meta[t] + mlr[0] * (om - meta[t]);
  nm = fminf(fmaxf(nm, 0.f), 2.f);
  meta_out[t] = nm;
  if (t < 1000) hist_out[t] = (t == ptr[0]) ? sc[1] : act[t];
}

__global__ __launch_bounds__(256) void neww_kernel(const float* __restrict__ W,
                                                   const float* __restrict__ outmean,
                                                   const float* __restrict__ posv,
                                                   const float* __restrict__ negh,
                                                   const float* __restrict__ xsum,
                                                   const float* __restrict__ scalep,
                                                   const float* __restrict__ win,
                                                   const float* __restrict__ dec,
                                                   float* __restrict__ out) {
  int idx4 = blockIdx.x * 256 + threadIdx.x;
  int rr = idx4 >> 8;
  int c4 = (idx4 & 255) * 4;
  float w99 = 0.01f * expf(-win[0] * dec[0]);
  float scale = scalep[0];
  float om_r = outmean[rr];
  float neg_r = negh[rr] + w99 * om_r;
  const float4 wv = *(const float4*)&W[(size_t)rr * H + c4];
  const float4 pv = *(const float4*)&posv[c4];
  const float4 xv = *(const float4*)&xsum[c4];
  float4 o;
  float vx[4] = {wv.x, wv.y, wv.z, wv.w};
  float px[4] = {pv.x, pv.y, pv.z, pv.w};
  float xx[4] = {xv.x, xv.y, xv.z, xv.w};
  float ox[4];
#pragma unroll
  for (int i = 0; i < 4; ++i) {
    float v = vx[i] + om_r * px[i] - neg_r * (xx[i] * (1.0f / (float)BATCH));
    v = fminf(fmaxf(v, -1.f), 1.f);
    v = v * scale;
    ox[i] = fminf(fmaxf(v, -1.f), 1.f);
  }
  o.x = ox[0]; o.y = ox[1]; o.z = ox[2]; o.w = ox[3];
  *(float4*)&out[(size_t)rr * H + c4] = o;
}

extern "C" void kernel_launch(void* const* d_in, const int* in_sizes, int n_in,
                              void* d_out, int out_size, void* d_ws, size_t ws_size,
                              hipStream_t stream) {
  const float* x     = (const float*)d_in[0];
  const float* W     = (const float*)d_in[1];
  const float* meta  = (const float*)d_in[2];
  const float* pre   = (const float*)d_in[3];
  const float* post  = (const float*)d_in[4];
  const float* act   = (const float*)d_in[5];
  const int*   ptr   = (const int*)d_in[6];
  const float* win   = (const float*)d_in[7];
  const float* dec   = (const float*)d_in[8];
  const float* targ  = (const float*)d_in[9];
  const float* homeo = (const float*)d_in[10];
  const float* mlr   = (const float*)d_in[11];

  float* out_y    = (float*)d_out;              // [B,H]
  float* out_w    = out_y + (size_t)BATCH * H;  // [H,H]
  float* out_meta = out_w + (size_t)H * H;      // [H]
  float* out_hist = out_meta + H;               // [1000]

  float* ws = (float*)d_ws;
  u16* Xb  = (u16*)(ws + WS_BF16);       // [B][H] bf16, 32 MB
  u16* Wbt = Xb + (size_t)BATCH * H;     // [H][H] bf16 transposed, 2 MB

  const size_t ws_need = (size_t)WS_BF16 * sizeof(float) +
                         ((size_t)BATCH * H + (size_t)H * H) * sizeof(u16);

  if (ws_size >= ws_need) {
    // fast path: 3 dispatches, no memset, no atomics
    prep_kernel<<<532, 256, 0, stream>>>(x, W, Xb, Wbt, ws, pre, post, win, dec);
    gemm_vm_kernel<<<1088, 256, 0, stream>>>(Xb, Wbt, meta, W, ws, out_y);
    tail_kernel<<<1024, 256, 0, stream>>>(W, meta, act, ptr, targ, homeo, mlr,
                                          win, dec, ws, out_w, out_meta, out_hist);
  } else {
    // legacy path (atomics, in-gemm conversion)
    float* xsum    = ws;
    float* outraw  = ws + 1024;
    float* outmean = ws + 2048;
    float* posv    = ws + 3072;
    float* negh    = ws + 4096;
    float* scalep  = ws + 5120;
    hipMemsetAsync(d_ws, 0, 6144 * sizeof(float), stream);
    colsum_kernel<<<dim3(4, 64), 256, 0, stream>>>(x, xsum);
    gemm_fallback_kernel<<<dim3(128, 8), 256, 0, stream>>>(x, W, meta, out_y);
    vecmat_kernel<<<dim3(4, 16), 256, 0, stream>>>(W, xsum, outraw);
    stdpvec_kernel<<<dim3(4, 5), 256, 0, stream>>>(pre, post, win, dec, posv, negh);
    finalize_kernel<<<1, 1024, 0, stream>>>(meta, act, ptr, targ, homeo, mlr,
                                            outraw, outmean, scalep, out_meta, out_hist);
    neww_kernel<<<1024, 256, 0, stream>>>(W, outmean, posv, negh, xsum, scalep, win, dec, out_w);
  }
}